// Round 12
// baseline (4587.506 us; speedup 1.0000x reference)
//
#include <hip/hip_runtime.h>

// Seq2Seq GRU + Bahdanau attention, fp32. B=32 S=64 T=48 E=512 H=1024 V=32000.
// R12: decoder = ONE fused kernel per step (h-dots+q | grid-barrier |
// attention x8-parts + xsum + finalize), encoder = 4 steps per launch with
// internal grid barriers. Barrier/visibility recipe validated in R5-R7:
// sc0sc1 write-through + syncthreads-drain before arrival; consumers
// first-touch-after-barrier plain loads; single-writer-full-line layouts.
// Logits: split-bf16 MFMA (R11, 355us, MfmaUtil 24%).

#define BB 32
#define SS 64
#define TT 48
#define TD 47
#define EE 512
#define HH 1024
#define GG 3072
#define VV 32000
#define SOS_IDX 1
#define MPAD 1536

typedef float f32x4 __attribute__((ext_vector_type(4)));
typedef short bf16x8 __attribute__((ext_vector_type(8)));

static __device__ __forceinline__ float sigmoid_f(float x) {
    return 1.0f / (1.0f + __expf(-x));
}
static __device__ __forceinline__ float tanh_f(float x) {
    return 1.0f - 2.0f / (__expf(2.0f * x) + 1.0f);
}
static __device__ __forceinline__ unsigned short f2bf(float f) {
    unsigned u = __float_as_uint(f);
    u = u + 0x7fffu + ((u >> 16) & 1u);
    return (unsigned short)(u >> 16);
}
// write-through stores: visible at device scope once vmcnt==0 (drained by
// the __syncthreads preceding barrier arrival).
static __device__ __forceinline__ void cst4(float* p, f32x4 v) {
    asm volatile("global_store_dwordx4 %0, %1, off sc0 sc1" :: "v"(p), "v"(v) : "memory");
}
static __device__ __forceinline__ void cst1(float* p, float v) {
    asm volatile("global_store_dword %0, %1, off sc0 sc1" :: "v"(p), "v"(v) : "memory");
}

// Two-level monotonic grid barrier (8 leaves + root), fence-free (R7).
static __device__ __forceinline__ void gbar(int* bar, int leafsz, int& bstep) {
    asm volatile("s_waitcnt vmcnt(0) lgkmcnt(0)" ::: "memory");
    __syncthreads();
    bstep += 1;
    if (threadIdx.x == 0) {
        int* leaf = bar + (blockIdx.x & 7) * 32;
        int* root = bar + 512;
        int lv = __hip_atomic_fetch_add(leaf, 1, __ATOMIC_RELAXED, __HIP_MEMORY_SCOPE_AGENT) + 1;
        if (lv == bstep * leafsz) {
            __hip_atomic_fetch_add(root, 1, __ATOMIC_RELAXED, __HIP_MEMORY_SCOPE_AGENT);
        }
        while (__hip_atomic_load(root, __ATOMIC_RELAXED, __HIP_MEMORY_SCOPE_AGENT) < bstep * 8) {
            __builtin_amdgcn_s_sleep(1);
        }
    }
    __syncthreads();
    asm volatile("" ::: "memory");
}

__global__ void k_dec_idx(const int* __restrict__ tgt, int* __restrict__ idx) {
    int m = blockIdx.x * 256 + threadIdx.x;
    if (m < TD * BB) {
        int t = m >> 5, b = m & 31;
        idx[m] = (t == 0) ? SOS_IDX : tgt[b * TT + t];
    }
}

// ---------------- fp32 128x128 GEMM ----------------
__global__ __launch_bounds__(256) void k_gemm128(
    const float* __restrict__ A, const float* __restrict__ Wt,
    const float* __restrict__ bias, float* __restrict__ C,
    const int* __restrict__ rowidx,
    int M, int N, int K, int lda, int ldw, int ldc)
{
    __shared__ __align__(16) float As[16][128];
    __shared__ __align__(16) float Bs[16][128];
    const int tid = threadIdx.x;
    const int tm = tid >> 4, tn = tid & 15;
    const int row0 = blockIdx.y * 128;
    const int col0 = blockIdx.x * 128;
    const int lr = tid >> 1;
    const int lq = tid & 1;

    long arow_off = -1;
    {
        int arow = row0 + lr;
        if (arow < M) {
            int r = rowidx ? rowidx[arow] : arow;
            arow_off = (long)r * lda;
        }
    }
    const long wrow_off = (long)(col0 + lr) * ldw;

    float acc[8][8];
#pragma unroll
    for (int i = 0; i < 8; ++i)
#pragma unroll
        for (int j = 0; j < 8; ++j) acc[i][j] = 0.f;

    for (int k0 = 0; k0 < K; k0 += 16) {
        f32x4 av0 = {0.f,0.f,0.f,0.f}, av1 = {0.f,0.f,0.f,0.f};
        if (arow_off >= 0) {
            av0 = *(const f32x4*)(A + arow_off + k0 + lq * 8);
            av1 = *(const f32x4*)(A + arow_off + k0 + lq * 8 + 4);
        }
        f32x4 wv0 = *(const f32x4*)(Wt + wrow_off + k0 + lq * 8);
        f32x4 wv1 = *(const f32x4*)(Wt + wrow_off + k0 + lq * 8 + 4);
        __syncthreads();
#pragma unroll
        for (int i = 0; i < 4; ++i) {
            As[lq * 8 + i][lr] = av0[i];
            As[lq * 8 + 4 + i][lr] = av1[i];
            Bs[lq * 8 + i][lr] = wv0[i];
            Bs[lq * 8 + 4 + i][lr] = wv1[i];
        }
        __syncthreads();
#pragma unroll
        for (int kk = 0; kk < 16; ++kk) {
            f32x4 a0 = *(const f32x4*)&As[kk][tm * 4];
            f32x4 a1 = *(const f32x4*)&As[kk][64 + tm * 4];
            f32x4 b0 = *(const f32x4*)&Bs[kk][tn * 4];
            f32x4 b1 = *(const f32x4*)&Bs[kk][64 + tn * 4];
            float a[8], b[8];
#pragma unroll
            for (int i = 0; i < 4; ++i) {
                a[i] = a0[i]; a[4 + i] = a1[i];
                b[i] = b0[i]; b[4 + i] = b1[i];
            }
#pragma unroll
            for (int i = 0; i < 8; ++i)
#pragma unroll
                for (int j = 0; j < 8; ++j) acc[i][j] += a[i] * b[j];
        }
    }

    f32x4 bv0 = {0.f,0.f,0.f,0.f}, bv1 = {0.f,0.f,0.f,0.f};
    if (bias) {
        bv0 = *(const f32x4*)(bias + col0 + tn * 4);
        bv1 = *(const f32x4*)(bias + col0 + 64 + tn * 4);
    }
#pragma unroll
    for (int i = 0; i < 8; ++i) {
        int m = row0 + ((i < 4) ? (tm * 4 + i) : (64 + tm * 4 + i - 4));
        if (m >= M) continue;
        f32x4 v0, v1;
#pragma unroll
        for (int j = 0; j < 4; ++j) {
            v0[j] = acc[i][j] + bv0[j];
            v1[j] = acc[i][4 + j] + bv1[j];
        }
        *(f32x4*)(C + (long)m * ldc + col0 + tn * 4) = v0;
        *(f32x4*)(C + (long)m * ldc + col0 + 64 + tn * 4) = v1;
    }
}

// ---------------- conversions for split-bf16 logits ----------------
__global__ __launch_bounds__(256) void k_cvtA(
    const float* __restrict__ A, unsigned short* __restrict__ Ah,
    unsigned short* __restrict__ Al)
{
    size_t i4 = ((size_t)blockIdx.x * 256 + threadIdx.x) * 4;
    int row = (int)(i4 >> 10);
    f32x4 v = {0.f, 0.f, 0.f, 0.f};
    if (row < TD * BB) v = *(const f32x4*)(A + i4);
    ushort4 h, l;
    float hf;
    h.x = f2bf(v.x); hf = __uint_as_float((unsigned)h.x << 16); l.x = f2bf(v.x - hf);
    h.y = f2bf(v.y); hf = __uint_as_float((unsigned)h.y << 16); l.y = f2bf(v.y - hf);
    h.z = f2bf(v.z); hf = __uint_as_float((unsigned)h.z << 16); l.z = f2bf(v.z - hf);
    h.w = f2bf(v.w); hf = __uint_as_float((unsigned)h.w << 16); l.w = f2bf(v.w - hf);
    *(ushort4*)(Ah + i4) = h;
    *(ushort4*)(Al + i4) = l;
}

__global__ __launch_bounds__(256) void k_cvtB(
    const float* __restrict__ Bsrc, unsigned short* __restrict__ Bh)
{
    size_t i4 = ((size_t)blockIdx.x * 256 + threadIdx.x) * 4;
    f32x4 v = *(const f32x4*)(Bsrc + i4);
    ushort4 h;
    h.x = f2bf(v.x); h.y = f2bf(v.y); h.z = f2bf(v.z); h.w = f2bf(v.w);
    *(ushort4*)(Bh + i4) = h;
}

// ---------------- split-bf16 MFMA logits GEMM (R11) ----------------
__global__ __launch_bounds__(256) void k_mfma_logits(
    const unsigned short* __restrict__ Ah,
    const unsigned short* __restrict__ Bh,
    const float* __restrict__ bo, float* __restrict__ C)
{
    __shared__ __align__(16) unsigned short As[128 * 64];
    __shared__ __align__(16) unsigned short Bs[128 * 64];
    const int tid = threadIdx.x;
    const int m0 = blockIdx.y * 128;
    const int n0 = blockIdx.x * 128;
    const int r = tid >> 1, half = tid & 1;
    const int lane = tid & 63, wid = tid >> 6;
    const int wm = wid >> 1, wn = wid & 1;

    f32x4 acc[4][4];
#pragma unroll
    for (int i = 0; i < 4; ++i)
#pragma unroll
        for (int j = 0; j < 4; ++j) acc[i][j] = (f32x4){0.f, 0.f, 0.f, 0.f};

    char* AsB = (char*)As;
    char* BsB = (char*)Bs;
    const int lwb = r * 128 + half * 64;
    const int swz = (r & 7) << 4;

    for (int kt = 0; kt < 32; ++kt) {
        const int kb = (kt & 15) * 64;
        const unsigned short* Ap = Ah + ((kt >> 4) ? (size_t)MPAD * 1024 : 0)
                                 + (size_t)(m0 + r) * 1024 + kb + half * 32;
        const unsigned short* Bp = Bh + (size_t)(n0 + r) * 1024 + kb + half * 32;
        f32x4 a0 = *(const f32x4*)(Ap + 0);
        f32x4 a1 = *(const f32x4*)(Ap + 8);
        f32x4 a2 = *(const f32x4*)(Ap + 16);
        f32x4 a3 = *(const f32x4*)(Ap + 24);
        f32x4 b0 = *(const f32x4*)(Bp + 0);
        f32x4 b1 = *(const f32x4*)(Bp + 8);
        f32x4 b2 = *(const f32x4*)(Bp + 16);
        f32x4 b3 = *(const f32x4*)(Bp + 24);
        __syncthreads();
        *(f32x4*)(AsB + ((lwb + 0)  ^ swz)) = a0;
        *(f32x4*)(AsB + ((lwb + 16) ^ swz)) = a1;
        *(f32x4*)(AsB + ((lwb + 32) ^ swz)) = a2;
        *(f32x4*)(AsB + ((lwb + 48) ^ swz)) = a3;
        *(f32x4*)(BsB + ((lwb + 0)  ^ swz)) = b0;
        *(f32x4*)(BsB + ((lwb + 16) ^ swz)) = b1;
        *(f32x4*)(BsB + ((lwb + 32) ^ swz)) = b2;
        *(f32x4*)(BsB + ((lwb + 48) ^ swz)) = b3;
        __syncthreads();
#pragma unroll
        for (int ks = 0; ks < 2; ++ks) {
            bf16x8 af[4], bf[4];
#pragma unroll
            for (int u = 0; u < 4; ++u) {
                int ml = wm * 64 + u * 16 + (lane & 15);
                int byteA = ml * 128 + ks * 64 + ((lane >> 4) << 4);
                af[u] = *(const bf16x8*)(AsB + (byteA ^ ((ml & 7) << 4)));
                int nl = wn * 64 + u * 16 + (lane & 15);
                int byteB = nl * 128 + ks * 64 + ((lane >> 4) << 4);
                bf[u] = *(const bf16x8*)(BsB + (byteB ^ ((nl & 7) << 4)));
            }
#pragma unroll
            for (int mi = 0; mi < 4; ++mi)
#pragma unroll
                for (int ni = 0; ni < 4; ++ni)
                    acc[mi][ni] = __builtin_amdgcn_mfma_f32_16x16x32_bf16(
                        af[mi], bf[ni], acc[mi][ni], 0, 0, 0);
        }
    }

    const int cl = lane & 15, rq = lane >> 4;
#pragma unroll
    for (int ni = 0; ni < 4; ++ni) {
        int col = n0 + wn * 64 + ni * 16 + cl;
        float bias = bo[col];
#pragma unroll
        for (int mi = 0; mi < 4; ++mi) {
#pragma unroll
            for (int j = 0; j < 4; ++j) {
                int m = m0 + wm * 64 + mi * 16 + rq * 4 + j;
                if (m < TD * BB) {
                    int orow = (m & 31) * TD + (m >> 5);
                    C[(size_t)orow * VV + col] = acc[mi][ni][j] + bias;
                }
            }
        }
    }
}

// ---------------- encoder: ns steps per launch ----------------
// 256 blocks x 512 thr; block owns 4 j-cols. h(s) at enc_out[b][s][:].
// Internal gbar between steps; enc_out written via write-through cst4,
// consumers first-touch lines only after the barrier (plain loads safe).
__global__ __launch_bounds__(512, 2) void k_enc_steps(
    const float* __restrict__ gi, const float* __restrict__ Whh,
    const float* __restrict__ bhh, float* __restrict__ enc_out,
    int s0, int ns, int* bar)
{
    __shared__ float red[12][16][32];
    __shared__ float sums[12][32];
    const int tid = threadIdx.x, bid = blockIdx.x;
    const int b = tid & 31, ks = tid >> 5;
    const int j0 = bid * 4;
    const int kc = ks * 64;
    int bstep = 0;

    for (int ss = 0; ss < ns; ++ss) {
        const int s = s0 + ss;
        float acc[12];
#pragma unroll
        for (int u = 0; u < 12; ++u) acc[u] = 0.f;
        if (s > 0) {
            f32x4 hreg[16];
            const float* hb = enc_out + ((size_t)b * SS + (s - 1)) * HH + kc;
#pragma unroll
            for (int i = 0; i < 16; ++i) hreg[i] = *(const f32x4*)(hb + (i << 2));
#pragma unroll
            for (int jj = 0; jj < 4; ++jj) {
                const float* pr = Whh + ((size_t)(j0 + jj) << 10) + kc;
                const float* pz = Whh + ((size_t)(HH + j0 + jj) << 10) + kc;
                const float* pn = Whh + ((size_t)(2 * HH + j0 + jj) << 10) + kc;
                float ar = 0.f, az = 0.f, an = 0.f;
#pragma unroll
                for (int i = 0; i < 16; ++i) {
                    f32x4 h4 = hreg[i];
                    f32x4 w;
                    w = *(const f32x4*)(pr + (i << 2));
                    ar += h4.x * w.x + h4.y * w.y + h4.z * w.z + h4.w * w.w;
                    w = *(const f32x4*)(pz + (i << 2));
                    az += h4.x * w.x + h4.y * w.y + h4.z * w.z + h4.w * w.w;
                    w = *(const f32x4*)(pn + (i << 2));
                    an += h4.x * w.x + h4.y * w.y + h4.z * w.z + h4.w * w.w;
                }
                acc[jj] = ar; acc[4 + jj] = az; acc[8 + jj] = an;
            }
        }
#pragma unroll
        for (int u = 0; u < 12; ++u) red[u][ks][b] = acc[u];
        __syncthreads();
        if (tid < 384) {
            int u = tid >> 5, fb = tid & 31;
            float x = 0.f;
#pragma unroll
            for (int q = 0; q < 16; ++q) x += red[u][q][fb];
            sums[u][fb] = x;
        }
        __syncthreads();
        if (tid < 32) {
            const f32x4 bh0 = *(const f32x4*)(bhh + j0);
            const f32x4 bh1 = *(const f32x4*)(bhh + HH + j0);
            const f32x4 bh2 = *(const f32x4*)(bhh + 2 * HH + j0);
            const float* gr = gi + (size_t)(tid * SS + s) * GG;
            f32x4 g0 = *(const f32x4*)(gr + j0);
            f32x4 g1 = *(const f32x4*)(gr + HH + j0);
            f32x4 g2 = *(const f32x4*)(gr + 2 * HH + j0);
            f32x4 hold = {0.f, 0.f, 0.f, 0.f};
            if (s > 0) hold = *(const f32x4*)(enc_out + ((size_t)tid * SS + (s - 1)) * HH + j0);
            f32x4 hn;
#pragma unroll
            for (int e = 0; e < 4; ++e) {
                float r = sigmoid_f(g0[e] + sums[e][tid] + bh0[e]);
                float z = sigmoid_f(g1[e] + sums[4 + e][tid] + bh1[e]);
                float n = tanh_f(g2[e] + r * (sums[8 + e][tid] + bh2[e]));
                hn[e] = (1.f - z) * n + z * hold[e];
            }
            cst4(enc_out + ((size_t)tid * SS + s) * HH + j0, hn);
        }
        if (ss != ns - 1) gbar(bar, 256 / 8, bstep);
    }
}

// ---------------- fused decoder step ----------------
// 256 blocks x 512 thr, ONE internal grid barrier.
// Phase A (all blocks): h-dots + q for 4 j-cols; write q2[bid][32][4] and
// hsums2[bid][12][32] via write-through (single-writer contiguous regions).
// Phase B (all blocks; ab=bid&31, part=bid>>5): redundant scores+softmax per
// part; xsum + gate finalize for j-slice [part*128, part*128+128).
__global__ __launch_bounds__(512, 2) void k_dec_step(
    const float* __restrict__ hbase, long hstride,
    const float* __restrict__ Whh, const float* __restrict__ wq,
    const float* __restrict__ bq, const float* __restrict__ keys,
    const float* __restrict__ wsv, const float* __restrict__ bsv,
    const int* __restrict__ src, const float* __restrict__ encproj,
    const float* __restrict__ gi, const float* __restrict__ bhh,
    float* __restrict__ q2, float* __restrict__ hsums2,
    float* __restrict__ h2all, float* __restrict__ attn_out,
    int t, int* bar)
{
    __shared__ float red[16][16][32];    // 32 KB; phase B aliases onto this
    __shared__ float qsum[4][32];
    const int tid = threadIdx.x, bid = blockIdx.x;
    const int b = tid & 31, ks = tid >> 5;
    const int j0 = bid * 4;
    const int kc = ks * 64;
    int bstep = 0;

    // ===== phase A =====
    {
        f32x4 hreg[16];
        const float* hb = hbase + (size_t)b * hstride + kc;
#pragma unroll
        for (int i = 0; i < 16; ++i) hreg[i] = *(const f32x4*)(hb + (i << 2));
        float acc[16];
#pragma unroll
        for (int jj = 0; jj < 4; ++jj) {
            const float* pr = Whh + ((size_t)(j0 + jj) << 10) + kc;
            const float* pz = Whh + ((size_t)(HH + j0 + jj) << 10) + kc;
            const float* pn = Whh + ((size_t)(2 * HH + j0 + jj) << 10) + kc;
            const float* pq = wq + ((size_t)(j0 + jj) << 10) + kc;
            float ar = 0.f, az = 0.f, an = 0.f, aq = 0.f;
#pragma unroll
            for (int i = 0; i < 16; ++i) {
                f32x4 h4 = hreg[i];
                f32x4 w;
                w = *(const f32x4*)(pr + (i << 2));
                ar += h4.x * w.x + h4.y * w.y + h4.z * w.z + h4.w * w.w;
                w = *(const f32x4*)(pz + (i << 2));
                az += h4.x * w.x + h4.y * w.y + h4.z * w.z + h4.w * w.w;
                w = *(const f32x4*)(pn + (i << 2));
                an += h4.x * w.x + h4.y * w.y + h4.z * w.z + h4.w * w.w;
                w = *(const f32x4*)(pq + (i << 2));
                aq += h4.x * w.x + h4.y * w.y + h4.z * w.z + h4.w * w.w;
            }
            acc[jj] = ar; acc[4 + jj] = az; acc[8 + jj] = an; acc[12 + jj] = aq;
        }
#pragma unroll
        for (int u = 0; u < 16; ++u) red[u][ks][b] = acc[u];
        __syncthreads();
        {
            int u = tid >> 5, fb = tid & 31;
            float x = 0.f;
#pragma unroll
            for (int q = 0; q < 16; ++q) x += red[u][q][fb];
            if (u < 12) cst1(hsums2 + (size_t)bid * 384 + u * 32 + fb, x);
            else qsum[u - 12][fb] = x;
        }
        __syncthreads();
        if (tid < 32) {
            const f32x4 bq4 = *(const f32x4*)(bq + j0);
            f32x4 qv;
            qv.x = qsum[0][tid] + bq4.x;
            qv.y = qsum[1][tid] + bq4.y;
            qv.z = qsum[2][tid] + bq4.z;
            qv.w = qsum[3][tid] + bq4.w;
            cst4(q2 + (size_t)bid * 128 + tid * 4, qv);
        }
    }
    gbar(bar, 256 / 8, bstep);

    // ===== phase B =====
    const int ab = bid & 31, part = bid >> 5;
    float* qs  = &red[0][0][0];   // [1024]
    float* wss = qs + 1024;       // [1024]
    float* scs = wss + 1024;      // [512]
    float* wl  = scs + 512;       // [64]
    float* xls = wl + 64;         // [384]
    if (tid < 256) {
        // q[ab][tid*4 .. +3] == q2[tid][ab][0..3]
        f32x4 qv = *(const f32x4*)(q2 + (size_t)tid * 128 + ab * 4);
        f32x4 wv = *(const f32x4*)(wsv + tid * 4);
        *(f32x4*)&qs[tid * 4] = qv;
        *(f32x4*)&wss[tid * 4] = wv;
    }
    __syncthreads();
    {
        const int s4 = tid >> 3, kq = tid & 7;
        const float* kr = keys + (size_t)(ab * SS + s4) * HH + kq * 128;
        float a = 0.f;
        for (int i = 0; i < 32; ++i) {
            f32x4 kv = *(const f32x4*)(kr + (i << 2));
            int k = kq * 128 + (i << 2);
            a += tanh_f(qs[k] + kv.x) * wss[k]
               + tanh_f(qs[k + 1] + kv.y) * wss[k + 1]
               + tanh_f(qs[k + 2] + kv.z) * wss[k + 2]
               + tanh_f(qs[k + 3] + kv.w) * wss[k + 3];
        }
        scs[kq * 64 + s4] = a;
    }
    __syncthreads();
    if (tid < 64) {
        float v = bsv[0];
#pragma unroll
        for (int q = 0; q < 8; ++q) v += scs[q * 64 + tid];
        bool valid = src[ab * SS + tid] != 0;
        float m = valid ? v : -3.0e38f;
        for (int off = 32; off; off >>= 1) m = fmaxf(m, __shfl_xor(m, off));
        float e = valid ? __expf(v - m) : 0.f;
        float ssum = e;
        for (int off = 32; off; off >>= 1) ssum += __shfl_xor(ssum, off);
        float wgt = e / ssum;
        wl[tid] = wgt;
        if (part == 0)
            attn_out[((size_t)ab * TD + t) * SS + tid] = wgt;
    }
    __syncthreads();
    if (tid < 384) {
        int gate = tid >> 7, jj = tid & 127;
        int col = (gate << 10) + (part << 7) + jj;
        float xa = 0.f;
        const float* ep = encproj + (size_t)ab * SS * GG + col;
        for (int s2 = 0; s2 < 64; ++s2)
            xa += wl[s2] * ep[(size_t)s2 * GG];
        xls[tid] = xa;
    }
    __syncthreads();
    if (tid < 128) {
        const int j = (part << 7) + tid;
        const int wbid = (part << 5) + (tid >> 2);   // writer block of this j
        const int jj = tid & 3;
        const float* hs = hsums2 + (size_t)wbid * 384;
        float sh0 = hs[(0 * 4 + jj) * 32 + ab];
        float sh1 = hs[(1 * 4 + jj) * 32 + ab];
        float sh2 = hs[(2 * 4 + jj) * 32 + ab];
        const float* gr = gi + (size_t)(t * BB + ab) * GG;
        float r = sigmoid_f(gr[j] + xls[tid] + sh0 + bhh[j]);
        float z = sigmoid_f(gr[HH + j] + xls[128 + tid] + sh1 + bhh[HH + j]);
        float n = tanh_f(gr[2 * HH + j] + xls[256 + tid] + r * (sh2 + bhh[2 * HH + j]));
        float hold = hbase[(size_t)ab * hstride + j];
        h2all[((size_t)t * BB + ab) * HH + j] = (1.f - z) * n + z * hold;
    }
}

extern "C" void kernel_launch(void* const* d_in, const int* in_sizes, int n_in,
                              void* d_out, int out_size, void* d_ws, size_t ws_size,
                              hipStream_t stream)
{
    const int*   src  = (const int*)d_in[0];
    const int*   tgt  = (const int*)d_in[1];
    const float* eemb = (const float*)d_in[2];
    const float* ewih = (const float*)d_in[3];
    const float* ewhh = (const float*)d_in[4];
    const float* ebih = (const float*)d_in[5];
    const float* ebhh = (const float*)d_in[6];
    const float* wq   = (const float*)d_in[7];
    const float* bq   = (const float*)d_in[8];
    const float* wk   = (const float*)d_in[9];
    const float* bk   = (const float*)d_in[10];
    const float* wsv  = (const float*)d_in[11];
    const float* bsv  = (const float*)d_in[12];
    const float* demb = (const float*)d_in[13];
    const float* dwih = (const float*)d_in[14];
    const float* dwhh = (const float*)d_in[15];
    const float* dbih = (const float*)d_in[16];
    const float* dbhh = (const float*)d_in[17];
    const float* wo   = (const float*)d_in[18];
    const float* bo   = (const float*)d_in[19];
    float* out = (float*)d_out;

    float* w = (float*)d_ws;
    float* enc_gi  = w;                                 // [B*S][3H]; later encproj
    float* dec_gi  = enc_gi  + (size_t)BB * SS * GG;    // [TD*B][3H]
    float* enc_out = dec_gi  + (size_t)TD * BB * GG;    // [B][S][H]
    float* keys    = enc_out + (size_t)BB * SS * HH;    // [B*S][H]
    float* h2all   = keys    + (size_t)BB * SS * HH;    // [TD][B][H]
    float* q2      = h2all   + (size_t)TD * BB * HH;    // [256][32][4]
    float* hsums2  = q2      + (size_t)256 * 128;       // [256][12][32]
    int*   didx    = (int*)(hsums2 + (size_t)256 * 384);// [TD*B]
    int*   barAll  = didx + TD * BB + 32;               // 63 regions x 576
    unsigned short* Ah = (unsigned short*)(barAll + 63 * 576 + 32);
    unsigned short* Al = Ah + (size_t)MPAD * 1024;
    // Bh overlays enc_gi..h2all (65.54 MB < 66.6 MB), used only after decoder.
    unsigned short* Bh = (unsigned short*)w;

    float* encproj = enc_gi;
    float* attn_out = out + (size_t)BB * TD * VV;

    hipMemsetAsync(barAll, 0, 63 * 576 * sizeof(int), stream);
    k_dec_idx<<<dim3((TD * BB + 255) / 256), 256, 0, stream>>>(tgt, didx);

    k_gemm128<<<dim3(GG / 128, (BB * SS) / 128), 256, 0, stream>>>(
        eemb, ewih, ebih, enc_gi, src, BB * SS, GG, EE, EE, EE, GG);
    k_gemm128<<<dim3(GG / 128, (TD * BB + 127) / 128), 256, 0, stream>>>(
        demb, dwih, dbih, dec_gi, didx, TD * BB, GG, EE, EE, EE + HH, GG);

    for (int i = 0; i < 16; ++i)
        k_enc_steps<<<dim3(256), dim3(512), 0, stream>>>(
            enc_gi, ewhh, ebhh, enc_out, i * 4, 4, barAll + i * 576);

    k_gemm128<<<dim3(HH / 128, (BB * SS) / 128), 256, 0, stream>>>(
        enc_out, wk, bk, keys, nullptr, BB * SS, HH, HH, HH, HH, HH);
    k_gemm128<<<dim3(GG / 128, (BB * SS) / 128), 256, 0, stream>>>(
        enc_out, dwih + EE, nullptr, encproj, nullptr,
        BB * SS, GG, HH, HH, EE + HH, GG);

    for (int t = 0; t < TD; ++t) {
        const float* hbase = (t == 0) ? enc_out + (size_t)(SS - 1) * HH
                                      : h2all + (size_t)(t - 1) * BB * HH;
        long hstride = (t == 0) ? (long)SS * HH : (long)HH;
        k_dec_step<<<dim3(256), dim3(512), 0, stream>>>(
            hbase, hstride, dwhh, wq, bq, keys, wsv, bsv, src, encproj,
            dec_gi, dbhh, q2, hsums2, h2all, attn_out, t, barAll + (16 + t) * 576);
    }

    k_cvtA<<<dim3(MPAD * 1024 / 1024), 256, 0, stream>>>(h2all, Ah, Al);
    k_cvtB<<<dim3(VV * 1024 / 1024), 256, 0, stream>>>(wo, Bh);
    k_mfma_logits<<<dim3(VV / 128, MPAD / 128), 256, 0, stream>>>(
        Ah, Bh, bo, out);
}